// Round 7
// baseline (265.872 us; speedup 1.0000x reference)
//
#include <hip/hip_runtime.h>
#include <hip/hip_bf16.h>

typedef __bf16 bf16;
typedef __attribute__((ext_vector_type(8))) __bf16 bf16x8;
typedef __attribute__((ext_vector_type(4))) __bf16 bf16x4;
typedef __attribute__((ext_vector_type(16))) float f32x16;

#define N_ROWS 16384
#define DIM 256
#define NT 128
#define LSTRIP 8
#define NSTRIPS 1088     /* sum_{it} ceil((128-it)/8) */
#define SQK1 4.53981608f /* sqrt(1/(0.07*ln2)): A pre-scaled so e^{z} = 2^{dot'} */
#define LN2F 0.69314718056f

#define WS_T_OFF (N_ROWS * DIM * 2)
#define WS_D_OFF (WS_T_OFF + N_ROWS * 4)

// Kernel 1: L2-normalize rows, scale by SQK1, emit bf16 A' to ws. Zeros T[]
// and d_out. Dg[row] = s2' = sum(bf16(SQK1*a)^2) = the MFMA diagonal, so the
// diagonal's bf16 rounding error cancels: loss_i = ln2*(log2(T'_i) - s2'_i).
__global__ void __launch_bounds__(256) normalize_kernel(const float* __restrict__ in,
                                                        bf16* __restrict__ out,
                                                        float* __restrict__ Tg,
                                                        float* __restrict__ Dg,
                                                        float* __restrict__ loss_out) {
    if (blockIdx.x == 0 && threadIdx.x == 0) loss_out[0] = 0.0f;
    if (blockIdx.x < 64) Tg[blockIdx.x * 256 + threadIdx.x] = 0.0f;

    const int row  = blockIdx.x * 4 + (threadIdx.x >> 6);
    const int lane = threadIdx.x & 63;
    const float4* rp = (const float4*)(in + (size_t)row * DIM);
    float4 v = rp[lane];
    float ss = v.x * v.x + v.y * v.y + v.z * v.z + v.w * v.w;
#pragma unroll
    for (int m = 1; m < 64; m <<= 1) ss += __shfl_xor(ss, m, 64);
    float inv = SQK1 / fmaxf(sqrtf(ss), 1e-12f);
    bf16x4 o;
    o[0] = (bf16)(v.x * inv);
    o[1] = (bf16)(v.y * inv);
    o[2] = (bf16)(v.z * inv);
    o[3] = (bf16)(v.w * inv);
    *(bf16x4*)(out + (size_t)row * DIM + lane * 4) = o;

    float f0 = (float)o[0], f1 = (float)o[1], f2 = (float)o[2], f3 = (float)o[3];
    float s2 = f0 * f0 + f1 * f1 + f2 * f2 + f3 * f3;
#pragma unroll
    for (int m = 1; m < 64; m <<= 1) s2 += __shfl_xor(s2, m, 64);
    if (lane == 0) Dg[row] = s2;
}

// Tree-reduce 16 floats across the 32 `lo` lanes; every lane ends with the
// full sum for register index r = (lo>>1)&15. (Correctness-proven R4-R6.)
#define TREE16(R, out)                                                     \
    do {                                                                   \
        float w8[8], w4[4], w2[2], w1, g_;                                 \
        _Pragma("unroll") for (int i_ = 0; i_ < 8; ++i_) {                 \
            g_ = (lo & 16) ? R[i_] : R[i_ + 8];                            \
            w8[i_] = ((lo & 16) ? R[i_ + 8] : R[i_]) + __shfl_xor(g_, 16); \
        }                                                                  \
        _Pragma("unroll") for (int i_ = 0; i_ < 4; ++i_) {                 \
            g_ = (lo & 8) ? w8[i_] : w8[i_ + 4];                           \
            w4[i_] = ((lo & 8) ? w8[i_ + 4] : w8[i_]) + __shfl_xor(g_, 8); \
        }                                                                  \
        _Pragma("unroll") for (int i_ = 0; i_ < 2; ++i_) {                 \
            g_ = (lo & 4) ? w4[i_] : w4[i_ + 2];                           \
            w2[i_] = ((lo & 4) ? w4[i_ + 2] : w4[i_]) + __shfl_xor(g_, 4); \
        }                                                                  \
        g_ = (lo & 2) ? w2[0] : w2[1];                                     \
        w1 = ((lo & 2) ? w2[1] : w2[0]) + __shfl_xor(g_, 2);               \
        out = w1 + __shfl_xor(w1, 1);                                      \
    } while (0)

// Kernel 2: symmetric A'A'^T + softmax denominator. No LDS. 512 thr = 8
// waves; tile 128x128: wave w = row-group (w>>2)*64 x col-group (w&3)*32.
// Per wave: af (64 rows x K=256, 128 VGPRs) loaded ONCE per strip via
// VOLATILE loads (compiler cannot rematerialize them -> stays register-
// resident; R6's plain loads were remat'd into the loop, VGPR_Count=116).
// Acc = 2x f32x16 (32), row-sum accumulators s0/s1 (32), depth-4 rotating
// B prefetch (16). B demand = 1 KB / 16 CU-cyc = 64 B/cyc/CU ~= L1 ceiling.
__global__ void __launch_bounds__(512, 2)
loss_kernel(const bf16* __restrict__ A, float* __restrict__ Tg) {
    const int tid = threadIdx.x;
    const int w  = tid >> 6;
    const int l  = tid & 63;
    const int lo = l & 31, hi = l >> 5;
    const int rg = w >> 2;   // row-group: 0/1 -> rows rg*64
    const int cg = w & 3;    // col-group: 0..3 -> cols cg*32

    // strip decode
    int it = 0, rem = blockIdx.x;
    for (;;) {
        int nch = (NT - it + LSTRIP - 1) / LSTRIP;
        if (rem < nch) break;
        rem -= nch;
        ++it;
    }
    const int jt0 = it + rem * LSTRIP;
    const int jt1 = (jt0 + LSTRIP < NT) ? (jt0 + LSTRIP) : NT;

    const int arow = rg * 64;

    // persistent A fragments (A-operand layout: m = lo, k = hi*8 + j)
    bf16x8 af0[16], af1[16];
    {
        const bf16* ap0 = A + (size_t)(it * 128 + arow + lo) * DIM + hi * 8;
#pragma unroll
        for (int k = 0; k < 16; ++k) {
            af0[k] = *(const volatile bf16x8*)(ap0 + k * 16);
            af1[k] = *(const volatile bf16x8*)(ap0 + 32 * DIM + k * 16);
        }
    }

    float s0[16], s1[16];
#pragma unroll
    for (int r = 0; r < 16; ++r) { s0[r] = 0.f; s1[r] = 0.f; }

    // B stream for this wave's 32 cols (B-operand: n = lo, k = hi*8 + j)
    const bf16* bb = A + (size_t)(jt0 * 128 + cg * 32 + lo) * DIM + hi * 8;
    bf16x8 buf[4];
#pragma unroll
    for (int q = 0; q < 4; ++q) buf[q] = *(const bf16x8*)(bb + q * 16);

    for (int jt = jt0; jt < jt1; ++jt) {
        const bf16* bbn = (jt + 1 < jt1) ? (bb + 128 * DIM) : bb;
        f32x16 c0, c1;
#pragma unroll
        for (int r = 0; r < 16; ++r) { c0[r] = 0.f; c1[r] = 0.f; }

#pragma unroll
        for (int k = 0; k < 16; ++k) {
            bf16x8 b = buf[k & 3];
            const bf16* pf = (k < 12) ? (bb + (k + 4) * 16) : (bbn + (k - 12) * 16);
            buf[k & 3] = *(const bf16x8*)pf;  // prefetch 4 steps ahead
            c0 = __builtin_amdgcn_mfma_f32_32x32x16_bf16(af0[k], b, c0, 0, 0, 0);
            c1 = __builtin_amdgcn_mfma_f32_32x32x16_bf16(af1[k], b, c1, 0, 0, 0);
        }

        // epilogue: e = 2^{dot'} (A pre-scaled; diagonal is the provable max)
        float cs = 0.f;
#pragma unroll
        for (int r = 0; r < 16; ++r) {
            float e0 = __builtin_amdgcn_exp2f(c0[r]);
            float e1 = __builtin_amdgcn_exp2f(c1[r]);
            s0[r] += e0;
            s1[r] += e1;
            cs += e0 + e1;
        }
        // col sum over the wave's 64 rows -> Tg[jt cols] (symmetry); skip diag
        cs += __shfl_xor(cs, 32);
        if (jt != it && hi == 0)
            atomicAdd(&Tg[jt * 128 + cg * 32 + lo], cs);
        bb = bbn;
    }

    // strip end: row sums (this wave's 32-col partials across all tiles).
    // C/D row = (r&3)+8*(r>>2)+4*hi; even lanes own c0 rows, odd own c1.
    float t0, t1;
    TREE16(s0, t0);
    TREE16(s1, t1);
    const int r = (lo >> 1) & 15;
    const int rowoff = (r & 3) + 8 * (r >> 2) + 4 * hi;
    atomicAdd(&Tg[it * 128 + arow + ((l & 1) ? 32 : 0) + rowoff], (l & 1) ? t1 : t0);
}

// Kernel 3: loss_i = ln2*(log2(T'_i) - s2'_i), mean over rows.
__global__ void __launch_bounds__(256) final_kernel(const float* __restrict__ Tg,
                                                    const float* __restrict__ Dg,
                                                    float* __restrict__ out) {
    __shared__ float red[4];
    const int i = blockIdx.x * 256 + threadIdx.x;
    float c = LN2F * (__log2f(Tg[i]) - Dg[i]) * (1.0f / (float)N_ROWS);
#pragma unroll
    for (int m = 1; m < 64; m <<= 1) c += __shfl_xor(c, m, 64);
    if ((threadIdx.x & 63) == 0) red[threadIdx.x >> 6] = c;
    __syncthreads();
    if (threadIdx.x == 0)
        atomicAdd(out, red[0] + red[1] + red[2] + red[3]);
}

extern "C" void kernel_launch(void* const* d_in, const int* in_sizes, int n_in,
                              void* d_out, int out_size, void* d_ws, size_t ws_size,
                              hipStream_t stream) {
    const float* emb = (const float*)d_in[0];
    float* out = (float*)d_out;
    bf16* Abf = (bf16*)d_ws;
    float* Tg = (float*)((char*)d_ws + WS_T_OFF);
    float* Dg = (float*)((char*)d_ws + WS_D_OFF);

    hipLaunchKernelGGL(normalize_kernel, dim3(N_ROWS / 4), dim3(256), 0, stream,
                       emb, Abf, Tg, Dg, out);
    hipLaunchKernelGGL(loss_kernel, dim3(NSTRIPS), dim3(512), 0, stream,
                       Abf, Tg);
    hipLaunchKernelGGL(final_kernel, dim3(N_ROWS / 256), dim3(256), 0, stream,
                       Tg, Dg, out);
}

// Round 8
// 196.677 us; speedup vs baseline: 1.3518x; 1.3518x over previous
//
#include <hip/hip_runtime.h>
#include <hip/hip_bf16.h>

typedef __bf16 bf16;
typedef __attribute__((ext_vector_type(8))) __bf16 bf16x8;
typedef __attribute__((ext_vector_type(4))) __bf16 bf16x4;
typedef __attribute__((ext_vector_type(16))) float f32x16;

#define N_ROWS 16384
#define DIM 256
#define NT 128
#define LSTRIP 8
#define NSTRIPS 1088     /* sum_{it} ceil((128-it)/8) */
#define SQK1 4.53981608f /* sqrt(1/(0.07*ln2)): A pre-scaled so e^{z} = 2^{dot'} */
#define LN2F 0.69314718056f

#define WS_T_OFF (N_ROWS * DIM * 2)
#define WS_D_OFF (WS_T_OFF + N_ROWS * 4)

#define GLOAD_LDS(g, l)                                        \
    __builtin_amdgcn_global_load_lds(                          \
        (const __attribute__((address_space(1))) void*)(g),    \
        (__attribute__((address_space(3))) void*)(l), 16, 0, 0)

// Kernel 1: L2-normalize rows, scale by SQK1, emit bf16 A' to ws. Zeros T[]
// and d_out. Dg[row] = s2' = sum(bf16(SQK1*a)^2) = the MFMA diagonal, so the
// diagonal's bf16 rounding error cancels: loss_i = ln2*(log2(T'_i) - s2'_i).
__global__ void __launch_bounds__(256) normalize_kernel(const float* __restrict__ in,
                                                        bf16* __restrict__ out,
                                                        float* __restrict__ Tg,
                                                        float* __restrict__ Dg,
                                                        float* __restrict__ loss_out) {
    if (blockIdx.x == 0 && threadIdx.x == 0) loss_out[0] = 0.0f;
    if (blockIdx.x < 64) Tg[blockIdx.x * 256 + threadIdx.x] = 0.0f;

    const int row  = blockIdx.x * 4 + (threadIdx.x >> 6);
    const int lane = threadIdx.x & 63;
    const float4* rp = (const float4*)(in + (size_t)row * DIM);
    float4 v = rp[lane];
    float ss = v.x * v.x + v.y * v.y + v.z * v.z + v.w * v.w;
#pragma unroll
    for (int m = 1; m < 64; m <<= 1) ss += __shfl_xor(ss, m, 64);
    float inv = SQK1 / fmaxf(sqrtf(ss), 1e-12f);
    bf16x4 o;
    o[0] = (bf16)(v.x * inv);
    o[1] = (bf16)(v.y * inv);
    o[2] = (bf16)(v.z * inv);
    o[3] = (bf16)(v.w * inv);
    *(bf16x4*)(out + (size_t)row * DIM + lane * 4) = o;

    float f0 = (float)o[0], f1 = (float)o[1], f2 = (float)o[2], f3 = (float)o[3];
    float s2 = f0 * f0 + f1 * f1 + f2 * f2 + f3 * f3;
#pragma unroll
    for (int m = 1; m < 64; m <<= 1) s2 += __shfl_xor(s2, m, 64);
    if (lane == 0) Dg[row] = s2;
}

// Tree-reduce 16 floats across the 32 `lo` lanes; every lane ends with the
// full sum for register index r = (lo>>1)&15. (Correctness-proven R4-R7.)
#define TREE16(R, out)                                                     \
    do {                                                                   \
        float w8[8], w4[4], w2[2], w1, g_;                                 \
        _Pragma("unroll") for (int i_ = 0; i_ < 8; ++i_) {                 \
            g_ = (lo & 16) ? R[i_] : R[i_ + 8];                            \
            w8[i_] = ((lo & 16) ? R[i_ + 8] : R[i_]) + __shfl_xor(g_, 16); \
        }                                                                  \
        _Pragma("unroll") for (int i_ = 0; i_ < 4; ++i_) {                 \
            g_ = (lo & 8) ? w8[i_] : w8[i_ + 4];                           \
            w4[i_] = ((lo & 8) ? w8[i_ + 4] : w8[i_]) + __shfl_xor(g_, 8); \
        }                                                                  \
        _Pragma("unroll") for (int i_ = 0; i_ < 2; ++i_) {                 \
            g_ = (lo & 4) ? w4[i_] : w4[i_ + 2];                           \
            w2[i_] = ((lo & 4) ? w4[i_ + 2] : w4[i_]) + __shfl_xor(g_, 4); \
        }                                                                  \
        g_ = (lo & 2) ? w2[0] : w2[1];                                     \
        w1 = ((lo & 2) ? w2[1] : w2[0]) + __shfl_xor(g_, 2);               \
        out = w1 + __shfl_xor(w1, 1);                                      \
    } while (0)

// Kernel 2: symmetric A'A'^T + softmax denominator.
// 512 thr = 8 waves = 2 row-groups x 4 col-groups on a 128x128 tile.
// af (64 rows x K=256) persistent in AGPRs (static indexing; proven R6/R7).
// B: full-K tile (128 cols x 256 = 64 KB) staged via global_load_lds w=16,
// double-buffered (128 KB LDS), XOR chunk-swizzle on the GLOBAL source side
// (LDS dest = uniform base + lane*16) -> bank-balanced ds_read_b128.
// Pipeline: raw s_barrier + s_waitcnt vmcnt(8) (R5-validated; prefetch for
// tile jt+1 stays in flight while computing tile jt — no full drain).
__global__ void __launch_bounds__(512, 1)
loss_kernel(const bf16* __restrict__ A, float* __restrict__ Tg) {
    __shared__ bf16 Bs[2][128 * DIM];  // 2 x 64 KB

    const int tid = threadIdx.x;
    const int w  = tid >> 6;
    const int l  = tid & 63;
    const int lo = l & 31, hi = l >> 5;
    const int rg = w >> 2;   // row-group: rows rg*64..+63
    const int cg = w & 3;    // col-group: cols cg*32..+31

    // strip decode
    int it = 0, rem = blockIdx.x;
    for (;;) {
        int nch = (NT - it + LSTRIP - 1) / LSTRIP;
        if (rem < nch) break;
        rem -= nch;
        ++it;
    }
    const int jt0 = it + rem * LSTRIP;
    const int jt1 = (jt0 + LSTRIP < NT) ? (jt0 + LSTRIP) : NT;

    const int arow = rg * 64;

    // persistent A fragments (A-operand: m = lo, k = hi*8 + j); static unroll
    bf16x8 af0[16], af1[16];
    {
        const bf16* ap0 = A + (size_t)(it * 128 + arow + lo) * DIM + hi * 8;
#pragma unroll
        for (int k = 0; k < 16; ++k) {
            af0[k] = *(const volatile bf16x8*)(ap0 + k * 16);
            af1[k] = *(const volatile bf16x8*)(ap0 + 32 * DIM + k * 16);
        }
    }

    float s0[16], s1[16];
#pragma unroll
    for (int r = 0; r < 16; ++r) { s0[r] = 0.f; s1[r] = 0.f; }

    // DMA lane constants. Wave w stages tile rows w*16..w*16+15 in 8 instrs
    // (2 rows each). Lane: rl = l>>5 (row in pair), s = l&31 (LDS slot).
    // Slot s of row r holds global chunk c = (s&24)|((s&7)^(r&7)).
    const int s_dma = l & 31;
    const int rl    = l >> 5;
    int vo[4];
#pragma unroll
    for (int j = 0; j < 4; ++j) {
        const int c = (s_dma & 24) | ((s_dma & 7) ^ ((j * 2 + rl) & 7));
        vo[j] = rl * DIM + c * 8;
    }

    // fragment-read constants: row = cg*32+lo; chunk cc at slot
    // (cc&24)|((cc&7)^(lo&7)); base in elements.
    const int rbase = (cg * 32 + lo) * DIM;
    const int mx7 = lo & 7;

#define ISSUE(jtn, bsel)                                                     \
    do {                                                                     \
        const bf16* tb_ = A + (size_t)(jtn) * 128 * DIM + (w * 16) * DIM;    \
        bf16* lb_ = &Bs[bsel][(w * 16) * DIM];                               \
        _Pragma("unroll") for (int q_ = 0; q_ < 8; ++q_) {                   \
            GLOAD_LDS(tb_ + (q_ * 2) * DIM + vo[q_ & 3],                     \
                      lb_ + (q_ * 2) * DIM);                                 \
        }                                                                    \
    } while (0)

    ISSUE(jt0, 0);
    for (int jt = jt0; jt < jt1; ++jt) {
        const int bsel = (jt - jt0) & 1;
        // barrier A: all waves done reading buf[bsel^1] (iter jt-1)
        asm volatile("s_barrier" ::: "memory");
        if (jt + 1 < jt1) {
            ISSUE(jt + 1, bsel ^ 1);
            asm volatile("s_waitcnt vmcnt(8)" ::: "memory");  // tile jt done
        } else {
            asm volatile("s_waitcnt vmcnt(0)" ::: "memory");
        }
        // barrier B: tile jt staged & visible to all waves
        asm volatile("s_barrier" ::: "memory");

        const bf16* bs = &Bs[bsel][0];
        f32x16 c0, c1;
#pragma unroll
        for (int r = 0; r < 16; ++r) { c0[r] = 0.f; c1[r] = 0.f; }

#pragma unroll
        for (int k = 0; k < 16; ++k) {
            const int cc = k * 2 + hi;
            const int slot = (cc & 24) | ((cc & 7) ^ mx7);
            bf16x8 b = *(const bf16x8*)&bs[rbase + slot * 8];
            c0 = __builtin_amdgcn_mfma_f32_32x32x16_bf16(af0[k], b, c0, 0, 0, 0);
            c1 = __builtin_amdgcn_mfma_f32_32x32x16_bf16(af1[k], b, c1, 0, 0, 0);
        }

        // epilogue: e = 2^{dot'} (A pre-scaled; diagonal is the provable max)
        float cs = 0.f;
#pragma unroll
        for (int r = 0; r < 16; ++r) {
            float e0 = __builtin_amdgcn_exp2f(c0[r]);
            float e1 = __builtin_amdgcn_exp2f(c1[r]);
            s0[r] += e0;
            s1[r] += e1;
            cs += e0 + e1;
        }
        // col sum over the wave's 64 rows -> Tg[jt cols] (symmetry); skip diag
        cs += __shfl_xor(cs, 32);
        if (jt != it && hi == 0)
            atomicAdd(&Tg[jt * 128 + cg * 32 + lo], cs);
    }

    // strip end: row sums. C/D row = (r&3)+8*(r>>2)+4*hi; even lanes own c0
    // rows, odd own c1 rows (+32).
    float t0, t1;
    TREE16(s0, t0);
    TREE16(s1, t1);
    const int r = (lo >> 1) & 15;
    const int rowoff = (r & 3) + 8 * (r >> 2) + 4 * hi;
    atomicAdd(&Tg[it * 128 + arow + ((l & 1) ? 32 : 0) + rowoff], (l & 1) ? t1 : t0);
#undef ISSUE
}

// Kernel 3: loss_i = ln2*(log2(T'_i) - s2'_i), mean over rows.
__global__ void __launch_bounds__(256) final_kernel(const float* __restrict__ Tg,
                                                    const float* __restrict__ Dg,
                                                    float* __restrict__ out) {
    __shared__ float red[4];
    const int i = blockIdx.x * 256 + threadIdx.x;
    float c = LN2F * (__log2f(Tg[i]) - Dg[i]) * (1.0f / (float)N_ROWS);
#pragma unroll
    for (int m = 1; m < 64; m <<= 1) c += __shfl_xor(c, m, 64);
    if ((threadIdx.x & 63) == 0) red[threadIdx.x >> 6] = c;
    __syncthreads();
    if (threadIdx.x == 0)
        atomicAdd(out, red[0] + red[1] + red[2] + red[3]);
}

extern "C" void kernel_launch(void* const* d_in, const int* in_sizes, int n_in,
                              void* d_out, int out_size, void* d_ws, size_t ws_size,
                              hipStream_t stream) {
    const float* emb = (const float*)d_in[0];
    float* out = (float*)d_out;
    bf16* Abf = (bf16*)d_ws;
    float* Tg = (float*)((char*)d_ws + WS_T_OFF);
    float* Dg = (float*)((char*)d_ws + WS_D_OFF);

    hipLaunchKernelGGL(normalize_kernel, dim3(N_ROWS / 4), dim3(256), 0, stream,
                       emb, Abf, Tg, Dg, out);
    hipLaunchKernelGGL(loss_kernel, dim3(NSTRIPS), dim3(512), 0, stream,
                       Abf, Tg);
    hipLaunchKernelGGL(final_kernel, dim3(N_ROWS / 256), dim3(256), 0, stream,
                       Tg, Dg, out);
}